// Round 5
// baseline (361.149 us; speedup 1.0000x reference)
//
#include <hip/hip_runtime.h>
#include <hip/hip_bf16.h>

#define B_   4
#define S_   2048
#define D_   1024
#define H_   16
#define DK_  64
#define NTOK 8192

typedef __bf16 bf16_t;
typedef __bf16 bf16x8 __attribute__((ext_vector_type(8)));
typedef __bf16 bf16x4 __attribute__((ext_vector_type(4)));
typedef __bf16 bf16x2 __attribute__((ext_vector_type(2)));
typedef float  f32x4  __attribute__((ext_vector_type(4)));
typedef float  f32x16 __attribute__((ext_vector_type(16)));
typedef unsigned u32x4 __attribute__((ext_vector_type(4)));
typedef int    i32x2  __attribute__((ext_vector_type(2)));

__device__ __forceinline__ void gll16(const void* g, void* l) {
  __builtin_amdgcn_global_load_lds(
      (const __attribute__((address_space(1))) void*)g,
      (__attribute__((address_space(3))) void*)l,
      16, 0, 0);
}

__device__ __forceinline__ f32x4 mfma32(bf16x8 a, bf16x8 b, f32x4 c) {
  return __builtin_amdgcn_mfma_f32_16x16x32_bf16(a, b, c, 0, 0, 0);
}

__device__ __forceinline__ f32x16 mfma32x32(bf16x8 a, bf16x8 b, f32x16 c) {
#if defined(__HIP_DEVICE_COMPILE__)
  return __builtin_amdgcn_mfma_f32_32x32x16_bf16(a, b, c, 0, 0, 0);
#else
  (void)a; (void)b;
  return c;
#endif
}

// Single-instruction v_exp_f32 (exp2f without -ffast-math takes the OCML
// precise path we don't need — P only has bf16 precision anyway).
__device__ __forceinline__ float fast_exp2(float x) {
#if defined(__HIP_DEVICE_COMPILE__) && __has_builtin(__builtin_amdgcn_exp2f)
  return __builtin_amdgcn_exp2f(x);
#else
  return exp2f(x);
#endif
}

__device__ __forceinline__ f32x16 zero16() {
  f32x16 z;
#pragma unroll
  for (int i = 0; i < 16; ++i) z[i] = 0.f;
  return z;
}

// pack two f32 -> one u32 of 2x bf16 (compiler emits v_cvt_pk_bf16_f32)
__device__ __forceinline__ unsigned pkbf(float lo, float hi) {
  bf16x2 t;
  t[0] = (bf16_t)lo;
  t[1] = (bf16_t)hi;
  return __builtin_bit_cast(unsigned, t);
}

// v_permlane32_swap_b32: exchanges vdst-high with vsrc-low.
// After plswap(x, y):  x = {lanes<32: x_old, lanes>=32: y_old[l-32]}  (both lows)
//                      y = {lanes<32: x_old[l+32], lanes>=32: y_old}  (both highs)
__device__ __forceinline__ void plswap(unsigned &x, unsigned &y) {
#if defined(__HIP_DEVICE_COMPILE__)
  i32x2 r = __builtin_amdgcn_permlane32_swap((int)x, (int)y, false, false);
  x = (unsigned)r[0];
  y = (unsigned)r[1];
#endif
}

// From one 32x32 S^T accumulator (rows = 32 kv, cols = 32 q; per-lane reg r
// holds kv_local = (r&3)+8*(r>>2)+4*hi for q = lane&31), produce the two
// K=16 B-operand fragments of P (p0: kv 0..15, p1: kv 16..31), exp2 applied.
__device__ __forceinline__ void build_pa(const f32x16 s, bf16x8 &p0, bf16x8 &p1) {
  unsigned A0 = pkbf(fast_exp2(s[0]),  fast_exp2(s[1]));
  unsigned A1 = pkbf(fast_exp2(s[2]),  fast_exp2(s[3]));
  unsigned B0 = pkbf(fast_exp2(s[4]),  fast_exp2(s[5]));
  unsigned B1 = pkbf(fast_exp2(s[6]),  fast_exp2(s[7]));
  unsigned C0 = pkbf(fast_exp2(s[8]),  fast_exp2(s[9]));
  unsigned C1 = pkbf(fast_exp2(s[10]), fast_exp2(s[11]));
  unsigned D0 = pkbf(fast_exp2(s[12]), fast_exp2(s[13]));
  unsigned D1 = pkbf(fast_exp2(s[14]), fast_exp2(s[15]));
  plswap(A0, B0);  // A0 -> word0 (k = hi*8+{0,1}), B0 -> word2 (k = hi*8+{4,5})
  plswap(A1, B1);  // A1 -> word1,                  B1 -> word3
  plswap(C0, D0);
  plswap(C1, D1);
  u32x4 lo = {A0, A1, B0, B1};
  u32x4 hi = {C0, C1, D0, D1};
  p0 = __builtin_bit_cast(bf16x8, lo);
  p1 = __builtin_bit_cast(bf16x8, hi);
}

// ---------------------------------------------------------------------------
// Kernel 0: fp32 -> bf16 cast of q,k,v activations.
// ---------------------------------------------------------------------------
__global__ __launch_bounds__(256) void tobf16(
    const float* __restrict__ q, const float* __restrict__ k,
    const float* __restrict__ v, bf16_t* __restrict__ o) {
  const float* src = (blockIdx.z == 0) ? q : (blockIdx.z == 1) ? k : v;
  bf16_t* dst = o + (size_t)blockIdx.z * 8388608;
  size_t i = ((size_t)blockIdx.x * 256 + threadIdx.x) * 4;
  float4 x = *(const float4*)&src[i];
  bf16x4 y;
  y[0] = (bf16_t)x.x; y[1] = (bf16_t)x.y;
  y[2] = (bf16_t)x.z; y[3] = (bf16_t)x.w;
  *(bf16x4*)&dst[i] = y;
}

// ---------------------------------------------------------------------------
// Kernel 1: transpose the 4 weight matrices to bf16 [z][n][k].
// ---------------------------------------------------------------------------
__global__ __launch_bounds__(256) void prep_weights(
    const float* __restrict__ wq, const float* __restrict__ wk,
    const float* __restrict__ wv, const float* __restrict__ wo,
    bf16_t* __restrict__ wtHi) {
  const int z = blockIdx.z;
  const float* W = (z == 0) ? wq : (z == 1) ? wk : (z == 2) ? wv : wo;
  const int k0 = blockIdx.x * 64;
  const int n0 = blockIdx.y * 64;
  const int t = threadIdx.x;
  __shared__ float T[64][65];
#pragma unroll
  for (int rr = 0; rr < 4; ++rr) {
    int row = rr * 16 + (t >> 4);
    int cc = (t & 15) * 4;
    const float4 v = *(const float4*)&W[(size_t)(k0 + row) * D_ + n0 + cc];
    T[row][cc + 0] = v.x; T[row][cc + 1] = v.y;
    T[row][cc + 2] = v.z; T[row][cc + 3] = v.w;
  }
  __syncthreads();
  const int n = t >> 2;
  const int kc = (t & 3) * 16;
  bf16x8 h0, h1;
#pragma unroll
  for (int j = 0; j < 16; ++j) {
    float vv = T[kc + j][n];
    if (j < 8) h0[j] = (bf16_t)vv;
    else       h1[j - 8] = (bf16_t)vv;
  }
  size_t ofs = (size_t)z * 1048576 + (size_t)(n0 + n) * D_ + k0 + kc;
  *(bf16x8*)&wtHi[ofs] = h0; *(bf16x8*)&wtHi[ofs + 8] = h1;
}

// ---------------------------------------------------------------------------
// Kernel 2a: QKV projection GEMM, bf16 A, single-term W.
// ---------------------------------------------------------------------------
__global__ __launch_bounds__(256) void gemm_qkv_bf16(
    const bf16_t* __restrict__ Abf,
    const float* __restrict__ bq, const float* __restrict__ bk,
    const float* __restrict__ bv,
    const bf16_t* __restrict__ wtHi, bf16_t* __restrict__ outQKV) {
  const int z = blockIdx.z;
  const bf16_t* A   = Abf + (size_t)z * 8388608;
  const float* bias = (z == 0) ? bq : (z == 1) ? bk : bv;
  const bf16_t* WHi = wtHi + (size_t)z * 1048576;
  bf16_t* Out = outQKV + (size_t)z * 8388608;

  const int row0 = blockIdx.x * 128;
  const int col0 = blockIdx.y * 128;
  const int t = threadIdx.x;
  const int w = t >> 6, L = t & 63;
  const int m = L & 15, g = L >> 4;

  __shared__ __align__(16) bf16_t As2[128 * 32];
  __shared__ __align__(16) bf16_t Whi_s[128 * 32];

  f32x4 acc[4][4];
#pragma unroll
  for (int i = 0; i < 4; ++i)
#pragma unroll
    for (int j = 0; j < 4; ++j) acc[i][j] = (f32x4){0.f, 0.f, 0.f, 0.f};

  const int aw0 = (w & 1) * 64;
  const int bw0 = (w >> 1) * 64;

  for (int kt = 0; kt < 32; ++kt) {
    const int k0 = kt * 32;
#pragma unroll
    for (int rr = 0; rr < 2; ++rr) {
      int lin16 = rr * 256 + t;
      int n = lin16 >> 2;
      int c = (lin16 & 3) ^ ((n >> 1) & 3);
      gll16(&A[(size_t)(row0 + n) * D_ + k0 + c * 8], &As2[rr * 2048 + w * 512]);
      gll16(&WHi[(size_t)(col0 + n) * D_ + k0 + c * 8], &Whi_s[rr * 2048 + w * 512]);
    }
    __syncthreads();

    bf16x8 af[4], wh[4];
#pragma unroll
    for (int it = 0; it < 4; ++it) {
      int row = aw0 + it * 16 + m;
      int sl = (g ^ ((m >> 1) & 3)) * 8;
      af[it] = *(const bf16x8*)&As2[row * 32 + sl];
    }
#pragma unroll
    for (int jt = 0; jt < 4; ++jt) {
      int n = bw0 + jt * 16 + m;
      int sl = (g ^ ((m >> 1) & 3)) * 8;
      wh[jt] = *(const bf16x8*)&Whi_s[n * 32 + sl];
    }
#pragma unroll
    for (int it = 0; it < 4; ++it)
#pragma unroll
      for (int jt = 0; jt < 4; ++jt)
        acc[it][jt] = mfma32(af[it], wh[jt], acc[it][jt]);
    __syncthreads();
  }
#pragma unroll
  for (int jt = 0; jt < 4; ++jt) {
    int col = col0 + bw0 + jt * 16 + m;
    float bcol = bias[col];
    int h = col >> 6, d = col & 63;
#pragma unroll
    for (int it = 0; it < 4; ++it) {
      if (z != 2) {
#pragma unroll
        for (int r = 0; r < 4; ++r) {
          int row = row0 + aw0 + it * 16 + g * 4 + r;
          int b = row >> 11, s = row & 2047;
          Out[((size_t)((b * H_ + h) * S_ + s)) * DK_ + d] =
              (bf16_t)(acc[it][jt][r] + bcol);
        }
      } else {
        int row = row0 + aw0 + it * 16 + g * 4;
        int b = row >> 11, s = row & 2047;
        bf16x4 p4;
#pragma unroll
        for (int r = 0; r < 4; ++r) p4[r] = (bf16_t)(acc[it][jt][r] + bcol);
        *(bf16x4*)&Out[((size_t)((b * H_ + h) * DK_ + d)) * S_ + s] = p4;
      }
    }
  }
}

// ---------------------------------------------------------------------------
// Kernel 2b: QKV projection GEMM, fp32 A fallback, single-term W.
// ---------------------------------------------------------------------------
__global__ __launch_bounds__(256) void gemm_qkv_f32(
    const float* __restrict__ Aq, const float* __restrict__ Ak,
    const float* __restrict__ Av,
    const float* __restrict__ bq, const float* __restrict__ bk,
    const float* __restrict__ bv,
    const bf16_t* __restrict__ wtHi, bf16_t* __restrict__ outQKV) {
  const int z = blockIdx.z;
  const float* A    = (z == 0) ? Aq : (z == 1) ? Ak : Av;
  const float* bias = (z == 0) ? bq : (z == 1) ? bk : bv;
  const bf16_t* WHi = wtHi + (size_t)z * 1048576;
  bf16_t* Out = outQKV + (size_t)z * 8388608;

  const int row0 = blockIdx.x * 128;
  const int col0 = blockIdx.y * 128;
  const int t = threadIdx.x;
  const int w = t >> 6, L = t & 63;
  const int m = L & 15, g = L >> 4;

  __shared__ __align__(16) float  As[128 * 32];
  __shared__ __align__(16) bf16_t Whi_s[128 * 32];

  f32x4 acc[4][4];
#pragma unroll
  for (int i = 0; i < 4; ++i)
#pragma unroll
    for (int j = 0; j < 4; ++j) acc[i][j] = (f32x4){0.f, 0.f, 0.f, 0.f};

  const int aw0 = (w & 1) * 64;
  const int bw0 = (w >> 1) * 64;

  for (int kt = 0; kt < 32; ++kt) {
    const int k0 = kt * 32;
#pragma unroll
    for (int rr = 0; rr < 4; ++rr) {
      int lin16 = rr * 256 + t;
      int row = lin16 >> 3;
      int c = (lin16 & 7) ^ (row & 7);
      gll16(&A[(size_t)(row0 + row) * D_ + k0 + c * 4], &As[rr * 1024 + w * 256]);
    }
#pragma unroll
    for (int rr = 0; rr < 2; ++rr) {
      int lin16 = rr * 256 + t;
      int n = lin16 >> 2;
      int c = (lin16 & 3) ^ ((n >> 1) & 3);
      gll16(&WHi[(size_t)(col0 + n) * D_ + k0 + c * 8], &Whi_s[rr * 2048 + w * 512]);
    }
    __syncthreads();

    bf16x8 af[4], wh[4];
#pragma unroll
    for (int it = 0; it < 4; ++it) {
      int row = aw0 + it * 16 + m;
      const f32x4* p = (const f32x4*)&As[row * 32];
      f32x4 x0 = p[(2 * g) ^ (m & 7)];
      f32x4 x1 = p[(2 * g + 1) ^ (m & 7)];
      bf16x8 a;
      a[0] = (bf16_t)x0.x; a[1] = (bf16_t)x0.y; a[2] = (bf16_t)x0.z; a[3] = (bf16_t)x0.w;
      a[4] = (bf16_t)x1.x; a[5] = (bf16_t)x1.y; a[6] = (bf16_t)x1.z; a[7] = (bf16_t)x1.w;
      af[it] = a;
    }
#pragma unroll
    for (int jt = 0; jt < 4; ++jt) {
      int n = bw0 + jt * 16 + m;
      int sl = (g ^ ((m >> 1) & 3)) * 8;
      wh[jt] = *(const bf16x8*)&Whi_s[n * 32 + sl];
    }
#pragma unroll
    for (int it = 0; it < 4; ++it)
#pragma unroll
      for (int jt = 0; jt < 4; ++jt)
        acc[it][jt] = mfma32(af[it], wh[jt], acc[it][jt]);
    __syncthreads();
  }
#pragma unroll
  for (int jt = 0; jt < 4; ++jt) {
    int col = col0 + bw0 + jt * 16 + m;
    float bcol = bias[col];
    int h = col >> 6, d = col & 63;
#pragma unroll
    for (int it = 0; it < 4; ++it) {
      if (z != 2) {
#pragma unroll
        for (int r = 0; r < 4; ++r) {
          int row = row0 + aw0 + it * 16 + g * 4 + r;
          int b = row >> 11, s = row & 2047;
          Out[((size_t)((b * H_ + h) * S_ + s)) * DK_ + d] =
              (bf16_t)(acc[it][jt][r] + bcol);
        }
      } else {
        int row = row0 + aw0 + it * 16 + g * 4;
        int b = row >> 11, s = row & 2047;
        bf16x4 p4;
#pragma unroll
        for (int r = 0; r < 4; ++r) p4[r] = (bf16_t)(acc[it][jt][r] + bcol);
        *(bf16x4*)&Out[((size_t)((b * H_ + h) * DK_ + d)) * S_ + s] = p4;
      }
    }
  }
}

// ---------------------------------------------------------------------------
// Kernel 3: flash attention on 32x32x16 MFMA (T12 structure), R1-proven body,
// restructured to 2-WAVE BLOCKS (q-tile 64) so each SIMD hosts waves from
// ~4 DIFFERENT barrier domains: independent blocks sit at staggered phases,
// so one wave's exp/cvt VALU chain overlaps another's MFMA burst without
// any intra-wave scheduling tricks (R2/R4's T15 attempt cost occupancy and
// lost; this keeps VGPR ~64 and raises block count 1024 -> 2048).
//  - XCD-chunked swizzle kept (FETCH 139 -> 24.6 MB measured, T1).
//  - single-buffered 16 KB LDS -> 8 blocks/CU; grid 2048 = 8/CU exactly.
// Q pre-scaled by 0.125*log2(e) so scores exit QK^T in log2 domain; raw
// v_exp_f32; P fragments assembled in-register via cvt_pk + permlane32_swap;
// denominator on the MFMA pipe via an all-ones A operand; PV computes O^T
// with V^T as the A operand so the per-lane output is row-major in d.
// ---------------------------------------------------------------------------
__global__ __launch_bounds__(128, 4) void attn(
    const bf16_t* __restrict__ Qh, const bf16_t* __restrict__ Kh,
    const bf16_t* __restrict__ VhT, bf16_t* __restrict__ Ohi) {
  // XCD swizzle: remap so each XCD owns 256 consecutive tiles = 8 whole
  // heads. grid = (32, 64) -> 2048 blocks, 2048 % 8 == 0 so bijective.
  const int lin = blockIdx.y * 32 + blockIdx.x;
  const int swz = (lin & 7) * 256 + (lin >> 3);
  const int bh = swz >> 5;
  const int q0 = (swz & 31) * 64;

  const int t = threadIdx.x, w = t >> 6;
  const int lane = t & 63;
  const int lo5 = lane & 31, hi = lane >> 5;

  __shared__ __align__(16) bf16_t Ks[64 * 64];  // [kv][d], xor-swizzled chunks
  __shared__ __align__(16) bf16_t Vt[64 * 64];  // [d][kv], xor-swizzled chunks

  const size_t qbase = (size_t)bh * S_ * DK_;
  const size_t vbase = (size_t)bh * DK_ * S_;

  // staging: 512 slots of 16B per tile; thread t covers slots {i*128 + t}.
  // LDS dest is wave-uniform base + lane*16 (slot == i*128 + w*64 + lane).
  int srow[4], scol[4];
#pragma unroll
  for (int i = 0; i < 4; ++i) {
    int slot = i * 128 + t;
    srow[i] = slot >> 3;
    scol[i] = (slot & 7) ^ (srow[i] & 7);
  }

  // Q fragments (B-operand): lane holds Q[q = qrow][dk = ks*16 + hi*8 + j],
  // pre-scaled by (1/sqrt(DK)) * log2(e)
  const int qrow = q0 + w * 32 + lo5;
  bf16x8 qf[4];
#pragma unroll
  for (int ks = 0; ks < 4; ++ks) {
    bf16x8 v = *(const bf16x8*)&Qh[qbase + (size_t)qrow * DK_ + ks * 16 + hi * 8];
#pragma unroll
    for (int j = 0; j < 8; ++j) v[j] = (bf16_t)(0.18033688f * (float)v[j]);
    qf[ks] = v;
  }

  bf16x8 ones;
#pragma unroll
  for (int j = 0; j < 8; ++j) ones[j] = (bf16_t)1.f;

  // Per-lane LDS element offsets, shared by Ks and Vt reads (rows 0..31;
  // +2048 elements reaches rows 32..63, same swizzle since 32 ≡ 0 mod 8).
  int offs[4];
#pragma unroll
  for (int ks = 0; ks < 4; ++ks)
    offs[ks] = lo5 * 64 + (((ks * 2 + hi) ^ (lo5 & 7)) * 8);

  f32x16 oacc0 = zero16(), oacc1 = zero16(), lacc = zero16();

  for (int kv0 = 0; kv0 < S_; kv0 += 64) {
#pragma unroll
    for (int i = 0; i < 4; ++i) {
      gll16(&Kh[qbase + (size_t)(kv0 + srow[i]) * DK_ + scol[i] * 8],
            &Ks[i * 1024 + w * 512]);
      gll16(&VhT[vbase + (size_t)srow[i] * S_ + kv0 + scol[i] * 8],
            &Vt[i * 1024 + w * 512]);
    }
    __syncthreads();

    // S^T (log2 domain): two 32x32 tiles, rows = kv, cols = q
    f32x16 sc0 = zero16(), sc1 = zero16();
#pragma unroll
    for (int ks = 0; ks < 4; ++ks) {
      bf16x8 k0 = *(const bf16x8*)&Ks[offs[ks]];
      bf16x8 k1 = *(const bf16x8*)&Ks[offs[ks] + 2048];
      sc0 = mfma32x32(k0, qf[ks], sc0);
      sc1 = mfma32x32(k1, qf[ks], sc1);
    }

    // P = 2^S packed to bf16 B-operand fragments (kv 16 per fragment)
    bf16x8 pa0, pa1, pa2, pa3;
    build_pa(sc0, pa0, pa1);
    build_pa(sc1, pa2, pa3);

    // PV + denominator, all on the MFMA pipe
#pragma unroll
    for (int ks = 0; ks < 4; ++ks) {
      bf16x8 pb = (ks == 0) ? pa0 : (ks == 1) ? pa1 : (ks == 2) ? pa2 : pa3;
      lacc = mfma32x32(ones, pb, lacc);
      bf16x8 v0 = *(const bf16x8*)&Vt[offs[ks]];
      bf16x8 v1 = *(const bf16x8*)&Vt[offs[ks] + 2048];
      oacc0 = mfma32x32(v0, pb, oacc0);
      oacc1 = mfma32x32(v1, pb, oacc1);
    }
    __syncthreads();
  }

  // epilogue: every lacc row is the full column sum — no reduction needed.
  // oacc reg r holds O^T[d][q]: q = lane&31, d = (r>>2)*8 + hi*4 + (r&3).
  const int b = bh >> 4, h = bh & 15;
  const float inv = 1.f / lacc[0];
  const size_t rowofs = ((size_t)(b * S_ + qrow)) * D_ + h * DK_;
#pragma unroll
  for (int rg = 0; rg < 4; ++rg) {
    bf16x4 o0, o1;
#pragma unroll
    for (int j = 0; j < 4; ++j) {
      o0[j] = (bf16_t)(oacc0[rg * 4 + j] * inv);
      o1[j] = (bf16_t)(oacc1[rg * 4 + j] * inv);
    }
    *(bf16x4*)&Ohi[rowofs + rg * 8 + hi * 4] = o0;
    *(bf16x4*)&Ohi[rowofs + 32 + rg * 8 + hi * 4] = o1;
  }
}

// ---------------------------------------------------------------------------
// Kernel 4: output projection, single-term bf16.
// ---------------------------------------------------------------------------
__global__ __launch_bounds__(256) void gemm_out(
    const bf16_t* __restrict__ Ahi, const bf16_t* __restrict__ wtHi,
    const float* __restrict__ bias, float* __restrict__ Out) {
  const bf16_t* WHi = wtHi + (size_t)3 * 1048576;
  const int row0 = blockIdx.x * 128;
  const int col0 = blockIdx.y * 128;
  const int t = threadIdx.x;
  const int w = t >> 6, L = t & 63;
  const int m = L & 15, g = L >> 4;

  __shared__ __align__(16) bf16_t Ahi_s[128 * 32];
  __shared__ __align__(16) bf16_t Whi_s[128 * 32];

  f32x4 acc[4][4];
#pragma unroll
  for (int i = 0; i < 4; ++i)
#pragma unroll
    for (int j = 0; j < 4; ++j) acc[i][j] = (f32x4){0.f, 0.f, 0.f, 0.f};

  const int aw0 = (w & 1) * 64;
  const int bw0 = (w >> 1) * 64;

  for (int kt = 0; kt < 32; ++kt) {
    const int k0 = kt * 32;
#pragma unroll
    for (int rr = 0; rr < 2; ++rr) {
      int lin16 = rr * 256 + t;
      int n = lin16 >> 2;
      int c = (lin16 & 3) ^ ((n >> 1) & 3);
      gll16(&Ahi[(size_t)(row0 + n) * D_ + k0 + c * 8], &Ahi_s[rr * 2048 + w * 512]);
      gll16(&WHi[(size_t)(col0 + n) * D_ + k0 + c * 8], &Whi_s[rr * 2048 + w * 512]);
    }
    __syncthreads();

    bf16x8 ah[4], wh[4];
#pragma unroll
    for (int it = 0; it < 4; ++it) {
      int row = aw0 + it * 16 + m;
      int sl = (g ^ ((m >> 1) & 3)) * 8;
      ah[it] = *(const bf16x8*)&Ahi_s[row * 32 + sl];
    }
#pragma unroll
    for (int jt = 0; jt < 4; ++jt) {
      int n = bw0 + jt * 16 + m;
      int sl = (g ^ ((m >> 1) & 3)) * 8;
      wh[jt] = *(const bf16x8*)&Whi_s[n * 32 + sl];
    }
#pragma unroll
    for (int it = 0; it < 4; ++it)
#pragma unroll
      for (int jt = 0; jt < 4; ++jt)
        acc[it][jt] = mfma32(ah[it], wh[jt], acc[it][jt]);
    __syncthreads();
  }
#pragma unroll
  for (int jt = 0; jt < 4; ++jt) {
    int col = col0 + bw0 + jt * 16 + m;
    float bcol = bias[col];
#pragma unroll
    for (int it = 0; it < 4; ++it)
#pragma unroll
      for (int r = 0; r < 4; ++r) {
        int row = row0 + aw0 + it * 16 + g * 4 + r;
        Out[(size_t)row * D_ + col] = acc[it][jt][r] + bcol;
      }
  }
}

// ---------------------------------------------------------------------------
extern "C" void kernel_launch(void* const* d_in, const int* in_sizes, int n_in,
                              void* d_out, int out_size, void* d_ws, size_t ws_size,
                              hipStream_t stream) {
  const float* q  = (const float*)d_in[0];
  const float* k  = (const float*)d_in[1];
  const float* v  = (const float*)d_in[2];
  const float* wq = (const float*)d_in[3];
  const float* bq = (const float*)d_in[4];
  const float* wk = (const float*)d_in[5];
  const float* bk = (const float*)d_in[6];
  const float* wv = (const float*)d_in[7];
  const float* bv = (const float*)d_in[8];
  const float* wo = (const float*)d_in[9];
  const float* bo = (const float*)d_in[10];
  float* out = (float*)d_out;

  char* ws = (char*)d_ws;
  bf16_t* wtHi = (bf16_t*)(ws);                      // 8 MB
  bf16_t* QKVh = (bf16_t*)(ws + (8ull << 20));       // 48 MB (Qh, Kh, VhT)
  bf16_t* Ohi  = (bf16_t*)(ws + (56ull << 20));      // 16 MB
  bf16_t* Abf  = (bf16_t*)(ws + (56ull << 20));      // 48 MB (overlaps Ohi)

  const bool big = ws_size >= (104ull << 20);

  hipLaunchKernelGGL(prep_weights, dim3(16, 16, 4), dim3(256), 0, stream,
                     wq, wk, wv, wo, wtHi);
  if (big) {
    hipLaunchKernelGGL(tobf16, dim3(8192, 1, 3), dim3(256), 0, stream,
                       q, k, v, Abf);
    hipLaunchKernelGGL(gemm_qkv_bf16, dim3(64, 8, 3), dim3(256), 0, stream,
                       Abf, bq, bk, bv, wtHi, QKVh);
  } else {
    hipLaunchKernelGGL(gemm_qkv_f32, dim3(64, 8, 3), dim3(256), 0, stream,
                       q, k, v, bq, bk, bv, wtHi, QKVh);
  }
  hipLaunchKernelGGL(attn, dim3(32, 64), dim3(128), 0, stream,
                     QKVh, QKVh + 8388608, QKVh + 16777216, Ohi);
  hipLaunchKernelGGL(gemm_out, dim3(64, 8), dim3(256), 0, stream,
                     Ohi, wtHi, bo, out);
}

// Round 7
// 339.559 us; speedup vs baseline: 1.0636x; 1.0636x over previous
//
#include <hip/hip_runtime.h>
#include <hip/hip_bf16.h>

#define B_   4
#define S_   2048
#define D_   1024
#define H_   16
#define DK_  64
#define NTOK 8192

typedef __bf16 bf16_t;
typedef __bf16 bf16x8 __attribute__((ext_vector_type(8)));
typedef __bf16 bf16x4 __attribute__((ext_vector_type(4)));
typedef __bf16 bf16x2 __attribute__((ext_vector_type(2)));
typedef float  f32x4  __attribute__((ext_vector_type(4)));
typedef float  f32x16 __attribute__((ext_vector_type(16)));
typedef unsigned u32x4 __attribute__((ext_vector_type(4)));
typedef int    i32x2  __attribute__((ext_vector_type(2)));

__device__ __forceinline__ void gll16(const void* g, void* l) {
  __builtin_amdgcn_global_load_lds(
      (const __attribute__((address_space(1))) void*)g,
      (__attribute__((address_space(3))) void*)l,
      16, 0, 0);
}

__device__ __forceinline__ f32x4 mfma32(bf16x8 a, bf16x8 b, f32x4 c) {
  return __builtin_amdgcn_mfma_f32_16x16x32_bf16(a, b, c, 0, 0, 0);
}

__device__ __forceinline__ f32x16 mfma32x32(bf16x8 a, bf16x8 b, f32x16 c) {
#if defined(__HIP_DEVICE_COMPILE__)
  return __builtin_amdgcn_mfma_f32_32x32x16_bf16(a, b, c, 0, 0, 0);
#else
  (void)a; (void)b;
  return c;
#endif
}

// Single-instruction v_exp_f32 (exp2f without -ffast-math takes the OCML
// precise path we don't need — P only has bf16 precision anyway).
__device__ __forceinline__ float fast_exp2(float x) {
#if defined(__HIP_DEVICE_COMPILE__) && __has_builtin(__builtin_amdgcn_exp2f)
  return __builtin_amdgcn_exp2f(x);
#else
  return exp2f(x);
#endif
}

__device__ __forceinline__ f32x16 zero16() {
  f32x16 z;
#pragma unroll
  for (int i = 0; i < 16; ++i) z[i] = 0.f;
  return z;
}

// pack two f32 -> one u32 of 2x bf16 (compiler emits v_cvt_pk_bf16_f32)
__device__ __forceinline__ unsigned pkbf(float lo, float hi) {
  bf16x2 t;
  t[0] = (bf16_t)lo;
  t[1] = (bf16_t)hi;
  return __builtin_bit_cast(unsigned, t);
}

// v_permlane32_swap_b32: exchanges vdst-high with vsrc-low.
// After plswap(x, y):  x = {lanes<32: x_old, lanes>=32: y_old[l-32]}  (both lows)
//                      y = {lanes<32: x_old[l+32], lanes>=32: y_old}  (both highs)
__device__ __forceinline__ void plswap(unsigned &x, unsigned &y) {
#if defined(__HIP_DEVICE_COMPILE__)
  i32x2 r = __builtin_amdgcn_permlane32_swap((int)x, (int)y, false, false);
  x = (unsigned)r[0];
  y = (unsigned)r[1];
#endif
}

// From one 32x32 S^T accumulator (rows = 32 kv, cols = 32 q; per-lane reg r
// holds kv_local = (r&3)+8*(r>>2)+4*hi for q = lane&31), produce the two
// K=16 B-operand fragments of P (p0: kv 0..15, p1: kv 16..31), exp2 applied.
__device__ __forceinline__ void build_pa(const f32x16 s, bf16x8 &p0, bf16x8 &p1) {
  unsigned A0 = pkbf(fast_exp2(s[0]),  fast_exp2(s[1]));
  unsigned A1 = pkbf(fast_exp2(s[2]),  fast_exp2(s[3]));
  unsigned B0 = pkbf(fast_exp2(s[4]),  fast_exp2(s[5]));
  unsigned B1 = pkbf(fast_exp2(s[6]),  fast_exp2(s[7]));
  unsigned C0 = pkbf(fast_exp2(s[8]),  fast_exp2(s[9]));
  unsigned C1 = pkbf(fast_exp2(s[10]), fast_exp2(s[11]));
  unsigned D0 = pkbf(fast_exp2(s[12]), fast_exp2(s[13]));
  unsigned D1 = pkbf(fast_exp2(s[14]), fast_exp2(s[15]));
  plswap(A0, B0);  // A0 -> word0 (k = hi*8+{0,1}), B0 -> word2 (k = hi*8+{4,5})
  plswap(A1, B1);  // A1 -> word1,                  B1 -> word3
  plswap(C0, D0);
  plswap(C1, D1);
  u32x4 lo = {A0, A1, B0, B1};
  u32x4 hi = {C0, C1, D0, D1};
  p0 = __builtin_bit_cast(bf16x8, lo);
  p1 = __builtin_bit_cast(bf16x8, hi);
}

// ---------------------------------------------------------------------------
// Kernel 0: fp32 -> bf16 cast of q,k,v activations.
// ---------------------------------------------------------------------------
__global__ __launch_bounds__(256) void tobf16(
    const float* __restrict__ q, const float* __restrict__ k,
    const float* __restrict__ v, bf16_t* __restrict__ o) {
  const float* src = (blockIdx.z == 0) ? q : (blockIdx.z == 1) ? k : v;
  bf16_t* dst = o + (size_t)blockIdx.z * 8388608;
  size_t i = ((size_t)blockIdx.x * 256 + threadIdx.x) * 4;
  float4 x = *(const float4*)&src[i];
  bf16x4 y;
  y[0] = (bf16_t)x.x; y[1] = (bf16_t)x.y;
  y[2] = (bf16_t)x.z; y[3] = (bf16_t)x.w;
  *(bf16x4*)&dst[i] = y;
}

// ---------------------------------------------------------------------------
// Kernel 1: transpose the 4 weight matrices to bf16 [z][n][k].
// ---------------------------------------------------------------------------
__global__ __launch_bounds__(256) void prep_weights(
    const float* __restrict__ wq, const float* __restrict__ wk,
    const float* __restrict__ wv, const float* __restrict__ wo,
    bf16_t* __restrict__ wtHi) {
  const int z = blockIdx.z;
  const float* W = (z == 0) ? wq : (z == 1) ? wk : (z == 2) ? wv : wo;
  const int k0 = blockIdx.x * 64;
  const int n0 = blockIdx.y * 64;
  const int t = threadIdx.x;
  __shared__ float T[64][65];
#pragma unroll
  for (int rr = 0; rr < 4; ++rr) {
    int row = rr * 16 + (t >> 4);
    int cc = (t & 15) * 4;
    const float4 v = *(const float4*)&W[(size_t)(k0 + row) * D_ + n0 + cc];
    T[row][cc + 0] = v.x; T[row][cc + 1] = v.y;
    T[row][cc + 2] = v.z; T[row][cc + 3] = v.w;
  }
  __syncthreads();
  const int n = t >> 2;
  const int kc = (t & 3) * 16;
  bf16x8 h0, h1;
#pragma unroll
  for (int j = 0; j < 16; ++j) {
    float vv = T[kc + j][n];
    if (j < 8) h0[j] = (bf16_t)vv;
    else       h1[j - 8] = (bf16_t)vv;
  }
  size_t ofs = (size_t)z * 1048576 + (size_t)(n0 + n) * D_ + k0 + kc;
  *(bf16x8*)&wtHi[ofs] = h0; *(bf16x8*)&wtHi[ofs + 8] = h1;
}

// ---------------------------------------------------------------------------
// Kernel 2a: QKV projection GEMM, bf16 A, BK=64.
// BK 32->64: halves the per-K-step vmcnt(0)+barrier drains (the ~20%
// structural stall of the m97-style loop) -> 32 MFMA per barrier pair.
// LDS 32 KB (2 x 128x64 bf16), staging/swizzle = the attn kernel's proven
// 8-chunk xor pattern (slot = chunk ^ (row&7); 2-way reads = free).
// ---------------------------------------------------------------------------
__global__ __launch_bounds__(256) void gemm_qkv_bf16(
    const bf16_t* __restrict__ Abf,
    const float* __restrict__ bq, const float* __restrict__ bk,
    const float* __restrict__ bv,
    const bf16_t* __restrict__ wtHi, bf16_t* __restrict__ outQKV) {
  const int z = blockIdx.z;
  const bf16_t* A   = Abf + (size_t)z * 8388608;
  const float* bias = (z == 0) ? bq : (z == 1) ? bk : bv;
  const bf16_t* WHi = wtHi + (size_t)z * 1048576;
  bf16_t* Out = outQKV + (size_t)z * 8388608;

  const int row0 = blockIdx.x * 128;
  const int col0 = blockIdx.y * 128;
  const int t = threadIdx.x;
  const int w = t >> 6, L = t & 63;
  const int m = L & 15, g = L >> 4;

  __shared__ __align__(16) bf16_t As2[128 * 64];
  __shared__ __align__(16) bf16_t Whi_s[128 * 64];

  f32x4 acc[4][4];
#pragma unroll
  for (int i = 0; i < 4; ++i)
#pragma unroll
    for (int j = 0; j < 4; ++j) acc[i][j] = (f32x4){0.f, 0.f, 0.f, 0.f};

  const int aw0 = (w & 1) * 64;
  const int bw0 = (w >> 1) * 64;

  // staging: 1024 chunks of 16B per tile; thread t covers chunks {i*256+t}.
  int srow[4], scol[4];
#pragma unroll
  for (int i = 0; i < 4; ++i) {
    int slot = i * 256 + t;
    srow[i] = slot >> 3;
    scol[i] = (slot & 7) ^ (srow[i] & 7);
  }

  for (int kt = 0; kt < 16; ++kt) {
    const int k0 = kt * 64;
#pragma unroll
    for (int i = 0; i < 4; ++i) {
      gll16(&A[(size_t)(row0 + srow[i]) * D_ + k0 + scol[i] * 8],
            &As2[i * 2048 + w * 512]);
      gll16(&WHi[(size_t)(col0 + srow[i]) * D_ + k0 + scol[i] * 8],
            &Whi_s[i * 2048 + w * 512]);
    }
    __syncthreads();

#pragma unroll
    for (int kh = 0; kh < 2; ++kh) {
      bf16x8 af[4], wh[4];
#pragma unroll
      for (int it = 0; it < 4; ++it) {
        int row = aw0 + it * 16 + m;
        int sl = ((kh * 4 + g) ^ (m & 7)) * 8;
        af[it] = *(const bf16x8*)&As2[row * 64 + sl];
      }
#pragma unroll
      for (int jt = 0; jt < 4; ++jt) {
        int n = bw0 + jt * 16 + m;
        int sl = ((kh * 4 + g) ^ (m & 7)) * 8;
        wh[jt] = *(const bf16x8*)&Whi_s[n * 64 + sl];
      }
#pragma unroll
      for (int it = 0; it < 4; ++it)
#pragma unroll
        for (int jt = 0; jt < 4; ++jt)
          acc[it][jt] = mfma32(af[it], wh[jt], acc[it][jt]);
    }
    __syncthreads();
  }
#pragma unroll
  for (int jt = 0; jt < 4; ++jt) {
    int col = col0 + bw0 + jt * 16 + m;
    float bcol = bias[col];
    int h = col >> 6, d = col & 63;
#pragma unroll
    for (int it = 0; it < 4; ++it) {
      if (z != 2) {
#pragma unroll
        for (int r = 0; r < 4; ++r) {
          int row = row0 + aw0 + it * 16 + g * 4 + r;
          int b = row >> 11, s = row & 2047;
          Out[((size_t)((b * H_ + h) * S_ + s)) * DK_ + d] =
              (bf16_t)(acc[it][jt][r] + bcol);
        }
      } else {
        int row = row0 + aw0 + it * 16 + g * 4;
        int b = row >> 11, s = row & 2047;
        bf16x4 p4;
#pragma unroll
        for (int r = 0; r < 4; ++r) p4[r] = (bf16_t)(acc[it][jt][r] + bcol);
        *(bf16x4*)&Out[((size_t)((b * H_ + h) * DK_ + d)) * S_ + s] = p4;
      }
    }
  }
}

// ---------------------------------------------------------------------------
// Kernel 2b: QKV projection GEMM, fp32 A fallback, single-term W (BK=32,
// unchanged — only used when the workspace is small).
// ---------------------------------------------------------------------------
__global__ __launch_bounds__(256) void gemm_qkv_f32(
    const float* __restrict__ Aq, const float* __restrict__ Ak,
    const float* __restrict__ Av,
    const float* __restrict__ bq, const float* __restrict__ bk,
    const float* __restrict__ bv,
    const bf16_t* __restrict__ wtHi, bf16_t* __restrict__ outQKV) {
  const int z = blockIdx.z;
  const float* A    = (z == 0) ? Aq : (z == 1) ? Ak : Av;
  const float* bias = (z == 0) ? bq : (z == 1) ? bk : bv;
  const bf16_t* WHi = wtHi + (size_t)z * 1048576;
  bf16_t* Out = outQKV + (size_t)z * 8388608;

  const int row0 = blockIdx.x * 128;
  const int col0 = blockIdx.y * 128;
  const int t = threadIdx.x;
  const int w = t >> 6, L = t & 63;
  const int m = L & 15, g = L >> 4;

  __shared__ __align__(16) float  As[128 * 32];
  __shared__ __align__(16) bf16_t Whi_s[128 * 32];

  f32x4 acc[4][4];
#pragma unroll
  for (int i = 0; i < 4; ++i)
#pragma unroll
    for (int j = 0; j < 4; ++j) acc[i][j] = (f32x4){0.f, 0.f, 0.f, 0.f};

  const int aw0 = (w & 1) * 64;
  const int bw0 = (w >> 1) * 64;

  for (int kt = 0; kt < 32; ++kt) {
    const int k0 = kt * 32;
#pragma unroll
    for (int rr = 0; rr < 4; ++rr) {
      int lin16 = rr * 256 + t;
      int row = lin16 >> 3;
      int c = (lin16 & 7) ^ (row & 7);
      gll16(&A[(size_t)(row0 + row) * D_ + k0 + c * 4], &As[rr * 1024 + w * 256]);
    }
#pragma unroll
    for (int rr = 0; rr < 2; ++rr) {
      int lin16 = rr * 256 + t;
      int n = lin16 >> 2;
      int c = (lin16 & 3) ^ ((n >> 1) & 3);
      gll16(&WHi[(size_t)(col0 + n) * D_ + k0 + c * 8], &Whi_s[rr * 2048 + w * 512]);
    }
    __syncthreads();

    bf16x8 af[4], wh[4];
#pragma unroll
    for (int it = 0; it < 4; ++it) {
      int row = aw0 + it * 16 + m;
      const f32x4* p = (const f32x4*)&As[row * 32];
      f32x4 x0 = p[(2 * g) ^ (m & 7)];
      f32x4 x1 = p[(2 * g + 1) ^ (m & 7)];
      bf16x8 a;
      a[0] = (bf16_t)x0.x; a[1] = (bf16_t)x0.y; a[2] = (bf16_t)x0.z; a[3] = (bf16_t)x0.w;
      a[4] = (bf16_t)x1.x; a[5] = (bf16_t)x1.y; a[6] = (bf16_t)x1.z; a[7] = (bf16_t)x1.w;
      af[it] = a;
    }
#pragma unroll
    for (int jt = 0; jt < 4; ++jt) {
      int n = bw0 + jt * 16 + m;
      int sl = (g ^ ((m >> 1) & 3)) * 8;
      wh[jt] = *(const bf16x8*)&Whi_s[n * 32 + sl];
    }
#pragma unroll
    for (int it = 0; it < 4; ++it)
#pragma unroll
      for (int jt = 0; jt < 4; ++jt)
        acc[it][jt] = mfma32(af[it], wh[jt], acc[it][jt]);
    __syncthreads();
  }
#pragma unroll
  for (int jt = 0; jt < 4; ++jt) {
    int col = col0 + bw0 + jt * 16 + m;
    float bcol = bias[col];
    int h = col >> 6, d = col & 63;
#pragma unroll
    for (int it = 0; it < 4; ++it) {
      if (z != 2) {
#pragma unroll
        for (int r = 0; r < 4; ++r) {
          int row = row0 + aw0 + it * 16 + g * 4 + r;
          int b = row >> 11, s = row & 2047;
          Out[((size_t)((b * H_ + h) * S_ + s)) * DK_ + d] =
              (bf16_t)(acc[it][jt][r] + bcol);
        }
      } else {
        int row = row0 + aw0 + it * 16 + g * 4;
        int b = row >> 11, s = row & 2047;
        bf16x4 p4;
#pragma unroll
        for (int r = 0; r < 4; ++r) p4[r] = (bf16_t)(acc[it][jt][r] + bcol);
        *(bf16x4*)&Out[((size_t)((b * H_ + h) * DK_ + d)) * S_ + s] = p4;
      }
    }
  }
}

// ---------------------------------------------------------------------------
// Kernel 3: flash attention on 32x32x16 MFMA (T12 structure) — EXACT revert
// to the measured-best config (Round-1 bench: 83.1-83.6 us, ~1035 TF issued):
// 4-wave/256-thread blocks, single-buffered 16 KB LDS, no dbuf, no XCD
// swizzle. Three scheduling variants (dbuf+swizzle, T15 deferred-PV, 2-wave
// blocks) all measured slower; this is the empirical optimum of the family.
// Q pre-scaled by 0.125*log2(e) so scores exit QK^T in log2 domain; raw
// v_exp_f32; P fragments assembled in-register via cvt_pk + permlane32_swap;
// denominator on the MFMA pipe via an all-ones A operand; PV computes O^T
// with V^T as the A operand so the per-lane output is row-major in d.
// ---------------------------------------------------------------------------
__global__ __launch_bounds__(256, 2) void attn(
    const bf16_t* __restrict__ Qh, const bf16_t* __restrict__ Kh,
    const bf16_t* __restrict__ VhT, bf16_t* __restrict__ Ohi) {
  const int bh = blockIdx.y;
  const int q0 = blockIdx.x * 128;
  const int t = threadIdx.x, w = t >> 6;
  const int lane = t & 63;
  const int lo5 = lane & 31, hi = lane >> 5;

  __shared__ __align__(16) bf16_t Ks[64 * 64];  // [kv][d], xor-swizzled chunks
  __shared__ __align__(16) bf16_t Vt[64 * 64];  // [d][kv], xor-swizzled chunks

  const size_t qbase = (size_t)bh * S_ * DK_;
  const size_t vbase = (size_t)bh * DK_ * S_;

  // Q fragments (B-operand): lane holds Q[q = qrow][dk = ks*16 + hi*8 + j],
  // pre-scaled by (1/sqrt(DK)) * log2(e)
  const int qrow = q0 + w * 32 + lo5;
  bf16x8 qf[4];
#pragma unroll
  for (int ks = 0; ks < 4; ++ks) {
    bf16x8 v = *(const bf16x8*)&Qh[qbase + (size_t)qrow * DK_ + ks * 16 + hi * 8];
#pragma unroll
    for (int j = 0; j < 8; ++j) v[j] = (bf16_t)(0.18033688f * (float)v[j]);
    qf[ks] = v;
  }

  bf16x8 ones;
#pragma unroll
  for (int j = 0; j < 8; ++j) ones[j] = (bf16_t)1.f;

  // Per-lane LDS element offsets, shared by Ks and Vt reads (rows 0..31;
  // +2048 elements reaches rows 32..63, same swizzle since 32 ≡ 0 mod 8).
  int offs[4];
#pragma unroll
  for (int ks = 0; ks < 4; ++ks)
    offs[ks] = lo5 * 64 + (((ks * 2 + hi) ^ (lo5 & 7)) * 8);

  f32x16 oacc0 = zero16(), oacc1 = zero16(), lacc = zero16();

  for (int kv0 = 0; kv0 < S_; kv0 += 64) {
#pragma unroll
    for (int rr = 0; rr < 2; ++rr) {
      int lin16 = rr * 256 + t;
      int rrow = lin16 >> 3;
      int c = (lin16 & 7) ^ (rrow & 7);
      gll16(&Kh[qbase + (size_t)(kv0 + rrow) * DK_ + c * 8], &Ks[rr * 2048 + w * 512]);
      gll16(&VhT[vbase + (size_t)rrow * S_ + kv0 + c * 8], &Vt[rr * 2048 + w * 512]);
    }
    __syncthreads();

    // S^T (log2 domain): two 32x32 tiles, rows = kv, cols = q
    f32x16 sc0 = zero16(), sc1 = zero16();
#pragma unroll
    for (int ks = 0; ks < 4; ++ks) {
      bf16x8 k0 = *(const bf16x8*)&Ks[offs[ks]];
      bf16x8 k1 = *(const bf16x8*)&Ks[offs[ks] + 2048];
      sc0 = mfma32x32(k0, qf[ks], sc0);
      sc1 = mfma32x32(k1, qf[ks], sc1);
    }

    // P = 2^S packed to bf16 B-operand fragments (kv 16 per fragment)
    bf16x8 pa0, pa1, pa2, pa3;
    build_pa(sc0, pa0, pa1);
    build_pa(sc1, pa2, pa3);

    // PV + denominator, all on the MFMA pipe
#pragma unroll
    for (int ks = 0; ks < 4; ++ks) {
      bf16x8 pb = (ks == 0) ? pa0 : (ks == 1) ? pa1 : (ks == 2) ? pa2 : pa3;
      lacc = mfma32x32(ones, pb, lacc);
      bf16x8 v0 = *(const bf16x8*)&Vt[offs[ks]];
      bf16x8 v1 = *(const bf16x8*)&Vt[offs[ks] + 2048];
      oacc0 = mfma32x32(v0, pb, oacc0);
      oacc1 = mfma32x32(v1, pb, oacc1);
    }
    __syncthreads();
  }

  // epilogue: every lacc row is the full column sum — no reduction needed.
  // oacc reg r holds O^T[d][q]: q = lane&31, d = (r>>2)*8 + hi*4 + (r&3).
  const int b = bh >> 4, h = bh & 15;
  const float inv = 1.f / lacc[0];
  const size_t rowofs = ((size_t)(b * S_ + qrow)) * D_ + h * DK_;
#pragma unroll
  for (int rg = 0; rg < 4; ++rg) {
    bf16x4 o0, o1;
#pragma unroll
    for (int j = 0; j < 4; ++j) {
      o0[j] = (bf16_t)(oacc0[rg * 4 + j] * inv);
      o1[j] = (bf16_t)(oacc1[rg * 4 + j] * inv);
    }
    *(bf16x4*)&Ohi[rowofs + rg * 8 + hi * 4] = o0;
    *(bf16x4*)&Ohi[rowofs + 32 + rg * 8 + hi * 4] = o1;
  }
}

// ---------------------------------------------------------------------------
// Kernel 4: output projection, single-term bf16, BK=64 (same change as 2a).
// ---------------------------------------------------------------------------
__global__ __launch_bounds__(256) void gemm_out(
    const bf16_t* __restrict__ Ahi, const bf16_t* __restrict__ wtHi,
    const float* __restrict__ bias, float* __restrict__ Out) {
  const bf16_t* WHi = wtHi + (size_t)3 * 1048576;
  const int row0 = blockIdx.x * 128;
  const int col0 = blockIdx.y * 128;
  const int t = threadIdx.x;
  const int w = t >> 6, L = t & 63;
  const int m = L & 15, g = L >> 4;

  __shared__ __align__(16) bf16_t Ahi_s[128 * 64];
  __shared__ __align__(16) bf16_t Whi_s[128 * 64];

  f32x4 acc[4][4];
#pragma unroll
  for (int i = 0; i < 4; ++i)
#pragma unroll
    for (int j = 0; j < 4; ++j) acc[i][j] = (f32x4){0.f, 0.f, 0.f, 0.f};

  const int aw0 = (w & 1) * 64;
  const int bw0 = (w >> 1) * 64;

  int srow[4], scol[4];
#pragma unroll
  for (int i = 0; i < 4; ++i) {
    int slot = i * 256 + t;
    srow[i] = slot >> 3;
    scol[i] = (slot & 7) ^ (srow[i] & 7);
  }

  for (int kt = 0; kt < 16; ++kt) {
    const int k0 = kt * 64;
#pragma unroll
    for (int i = 0; i < 4; ++i) {
      gll16(&Ahi[(size_t)(row0 + srow[i]) * D_ + k0 + scol[i] * 8],
            &Ahi_s[i * 2048 + w * 512]);
      gll16(&WHi[(size_t)(col0 + srow[i]) * D_ + k0 + scol[i] * 8],
            &Whi_s[i * 2048 + w * 512]);
    }
    __syncthreads();

#pragma unroll
    for (int kh = 0; kh < 2; ++kh) {
      bf16x8 ah[4], wh[4];
#pragma unroll
      for (int it = 0; it < 4; ++it) {
        int row = aw0 + it * 16 + m;
        int sl = ((kh * 4 + g) ^ (m & 7)) * 8;
        ah[it] = *(const bf16x8*)&Ahi_s[row * 64 + sl];
      }
#pragma unroll
      for (int jt = 0; jt < 4; ++jt) {
        int n = bw0 + jt * 16 + m;
        int sl = ((kh * 4 + g) ^ (m & 7)) * 8;
        wh[jt] = *(const bf16x8*)&Whi_s[n * 64 + sl];
      }
#pragma unroll
      for (int it = 0; it < 4; ++it)
#pragma unroll
        for (int jt = 0; jt < 4; ++jt)
          acc[it][jt] = mfma32(ah[it], wh[jt], acc[it][jt]);
    }
    __syncthreads();
  }
#pragma unroll
  for (int jt = 0; jt < 4; ++jt) {
    int col = col0 + bw0 + jt * 16 + m;
    float bcol = bias[col];
#pragma unroll
    for (int it = 0; it < 4; ++it)
#pragma unroll
      for (int r = 0; r < 4; ++r) {
        int row = row0 + aw0 + it * 16 + g * 4 + r;
        Out[(size_t)row * D_ + col] = acc[it][jt][r] + bcol;
      }
  }
}

// ---------------------------------------------------------------------------
extern "C" void kernel_launch(void* const* d_in, const int* in_sizes, int n_in,
                              void* d_out, int out_size, void* d_ws, size_t ws_size,
                              hipStream_t stream) {
  const float* q  = (const float*)d_in[0];
  const float* k  = (const float*)d_in[1];
  const float* v  = (const float*)d_in[2];
  const float* wq = (const float*)d_in[3];
  const float* bq = (const float*)d_in[4];
  const float* wk = (const float*)d_in[5];
  const float* bk = (const float*)d_in[6];
  const float* wv = (const float*)d_in[7];
  const float* bv = (const float*)d_in[8];
  const float* wo = (const float*)d_in[9];
  const float* bo = (const float*)d_in[10];
  float* out = (float*)d_out;

  char* ws = (char*)d_ws;
  bf16_t* wtHi = (bf16_t*)(ws);                      // 8 MB
  bf16_t* QKVh = (bf16_t*)(ws + (8ull << 20));       // 48 MB (Qh, Kh, VhT)
  bf16_t* Ohi  = (bf16_t*)(ws + (56ull << 20));      // 16 MB
  bf16_t* Abf  = (bf16_t*)(ws + (56ull << 20));      // 48 MB (overlaps Ohi)

  const bool big = ws_size >= (104ull << 20);

  hipLaunchKernelGGL(prep_weights, dim3(16, 16, 4), dim3(256), 0, stream,
                     wq, wk, wv, wo, wtHi);
  if (big) {
    hipLaunchKernelGGL(tobf16, dim3(8192, 1, 3), dim3(256), 0, stream,
                       q, k, v, Abf);
    hipLaunchKernelGGL(gemm_qkv_bf16, dim3(64, 8, 3), dim3(256), 0, stream,
                       Abf, bq, bk, bv, wtHi, QKVh);
  } else {
    hipLaunchKernelGGL(gemm_qkv_f32, dim3(64, 8, 3), dim3(256), 0, stream,
                       q, k, v, bq, bk, bv, wtHi, QKVh);
  }
  hipLaunchKernelGGL(attn, dim3(16, 64), dim3(256), 0, stream,
                     QKVh, QKVh + 8388608, QKVh + 16777216, Ohi);
  hipLaunchKernelGGL(gemm_out, dim3(64, 8), dim3(256), 0, stream,
                     Ohi, wtHi, bo, out);
}